// Round 5
// baseline (182.283 us; speedup 1.0000x reference)
//
#include <hip/hip_runtime.h>

#define SDIM 4096
#define ALPHA 0.01f
#define WS_LOG 8                      // 64 per-block log partials at [8..72)
#define WS_ARR 128                    // gathered column arrays
#define WS_PART (WS_ARR + 5 * SDIM)   // per-block partials (2 * 2048 floats)
#define NPART 2048                    // k_main block count

// ws layout (floats):
//   [8..72)                  64 per-block log partials (k_gather)
//   [128 .. 128+5*4096)      c0 | c1 | c3 | t0 | t1  (gathered columns)
//   [WS_PART .. +2048)       per-block sum_sq partials (k_main)
//   [WS_PART+2048 .. +4096)  per-block sum3 partials   (k_main)

// ---------------------------------------------------------------------------
// Kernel 1: gather columns, compute log partials.
// grid = 64 blocks x 64 threads (one wave per block, one thread per row).
// ---------------------------------------------------------------------------
__global__ void k_gather(const float* __restrict__ inp, const float* __restrict__ tgt,
                         float* __restrict__ ws) {
    int n = blockIdx.x * 64 + threadIdx.x;  // 0..4095
    const float* row = inp + (size_t)n * SDIM;
    const float* trow = tgt + (size_t)n * SDIM;
    float* arr = ws + WS_ARR;

    float v0 = row[0], v1 = row[1], v3 = row[3], v4 = row[4];
    arr[n]            = v0;            // c0
    arr[SDIM + n]     = v1;            // c1
    arr[2 * SDIM + n] = v3;            // c3
    arr[3 * SDIM + n] = trow[0];       // t0
    arr[4 * SDIM + n] = trow[1];       // t1

    float lg = logf(v4);
    #pragma unroll
    for (int off = 32; off > 0; off >>= 1) lg += __shfl_down(lg, off);
    if (threadIdx.x == 0) ws[WS_LOG + blockIdx.x] = lg;
}

// ---------------------------------------------------------------------------
// Kernel 2 (fused, row-tiled): block = 8 rows x 1024 cols.
// grid = (4 col-chunks, 512 row-tiles), 256 threads.
// Thread's column data (t0/t1/c3 float4) loaded ONCE and reused across the
// 8 rows — kills the ~200 MB of redundant column-array traffic that bounded
// R3/R4. Per row-iter: 2 HBM float4 loads + 4 dword cost stores (stores
// depend only on preloaded registers -> issue ahead of loads).
// ---------------------------------------------------------------------------
__global__ void __launch_bounds__(256) k_main(const float* __restrict__ inp,
                                              const float* __restrict__ tgt,
                                              const float* __restrict__ ws,
                                              float* __restrict__ out,
                                              float* __restrict__ wpart) {
    __shared__ float s1[4], s2[4];
    const float* c0 = ws + WS_ARR;
    const float* c1 = c0 + SDIM;
    const float* c3 = c0 + 2 * SDIM;
    const float* t0 = c0 + 3 * SDIM;
    const float* t1 = c0 + 4 * SDIM;

    int t = threadIdx.x;
    int col = blockIdx.x * 1024 + t * 4;
    int row0 = blockIdx.y * 8;

    // row-invariant column data: 3 float4, kept in registers for all 8 rows
    float4 f0 = *(const float4*)(t0 + col);
    float4 f1 = *(const float4*)(t1 + col);
    float4 fc = *(const float4*)(c3 + col);

    float a1 = 0.0f, a2 = 0.0f;
    #pragma unroll
    for (int r = 0; r < 8; ++r) {
        int n = row0 + r;
        const float* irow = inp + (size_t)n * SDIM + col;
        const float* trow = tgt + (size_t)n * SDIM + col;
        float4 vi = *(const float4*)irow;   // HBM
        float4 vt = *(const float4*)trow;   // HBM
        float c0r = c0[n];                  // wave-uniform -> scalar load
        float c1r = c1[n];

        // cost: depends only on preloaded regs + scalars
        float e0, e1;
        float* orow = out + 1 + (size_t)n * SDIM + col;
        e0 = c0r - f0.x; e1 = c1r - f1.x; orow[0] = 0.5f * (e0 * e0 + e1 * e1);
        e0 = c0r - f0.y; e1 = c1r - f1.y; orow[1] = 0.5f * (e0 * e0 + e1 * e1);
        e0 = c0r - f0.z; e1 = c1r - f1.z; orow[2] = 0.5f * (e0 * e0 + e1 * e1);
        e0 = c0r - f0.w; e1 = c1r - f1.w; orow[3] = 0.5f * (e0 * e0 + e1 * e1);

        float d;
        d = vi.x - vt.x; a1 += d * d;
        d = vi.y - vt.y; a1 += d * d;
        d = vi.z - vt.z; a1 += d * d;
        d = vi.w - vt.w; a1 += d * d;
        d = fc.x - vt.x; a2 += d * d;
        d = fc.y - vt.y; a2 += d * d;
        d = fc.z - vt.z; a2 += d * d;
        d = fc.w - vt.w; a2 += d * d;
    }

    // ---- block reduction of partials (no atomics) ----
    #pragma unroll
    for (int off = 32; off > 0; off >>= 1) {
        a1 += __shfl_down(a1, off);
        a2 += __shfl_down(a2, off);
    }
    int wave = t >> 6;
    if ((t & 63) == 0) { s1[wave] = a1; s2[wave] = a2; }
    __syncthreads();
    if (t == 0) {
        int idx = blockIdx.y * 4 + blockIdx.x;  // 0..2047
        wpart[idx]         = s1[0] + s1[1] + s1[2] + s1[3];
        wpart[NPART + idx] = s2[0] + s2[1] + s2[2] + s2[3];
    }
}

// ---------------------------------------------------------------------------
// Kernel 3: reduce the 2*NPART partials + 64 log partials, emit loss.
//   loss = ALPHA * sum_sq - S * sum_log + sum3 / (S*S)
// ---------------------------------------------------------------------------
__global__ void k_final(const float* __restrict__ ws, float* __restrict__ out) {
    __shared__ float s1[4], s2[4];
    float a1 = 0.0f, a2 = 0.0f;
    const float* wpart = ws + WS_PART;
    for (int i = threadIdx.x; i < NPART; i += 256) {
        a1 += wpart[i];
        a2 += wpart[NPART + i];
    }
    #pragma unroll
    for (int off = 32; off > 0; off >>= 1) {
        a1 += __shfl_down(a1, off);
        a2 += __shfl_down(a2, off);
    }
    int wave = threadIdx.x >> 6;
    if ((threadIdx.x & 63) == 0) { s1[wave] = a1; s2[wave] = a2; }
    __syncthreads();
    if (threadIdx.x == 0) {
        float sum_sq = s1[0] + s1[1] + s1[2] + s1[3];
        float sum3   = s2[0] + s2[1] + s2[2] + s2[3];
        float slog = 0.0f;
        #pragma unroll
        for (int i = 0; i < 64; ++i) slog += ws[WS_LOG + i];
        out[0] = ALPHA * sum_sq - (float)SDIM * slog
               + sum3 * (1.0f / ((float)SDIM * (float)SDIM));
    }
}

extern "C" void kernel_launch(void* const* d_in, const int* in_sizes, int n_in,
                              void* d_out, int out_size, void* d_ws, size_t ws_size,
                              hipStream_t stream) {
    const float* inp = (const float*)d_in[0];
    const float* tgt = (const float*)d_in[1];
    float* out = (float*)d_out;
    float* ws  = (float*)d_ws;

    k_gather<<<64, 64, 0, stream>>>(inp, tgt, ws);
    k_main<<<dim3(4, 512), 256, 0, stream>>>(inp, tgt, ws, out, ws + WS_PART);
    k_final<<<1, 256, 0, stream>>>(ws, out);
}